// Round 1
// 611.467 us; speedup vs baseline: 1.1901x; 1.1901x over previous
//
#include <hip/hip_runtime.h>
#include <hip/hip_bf16.h>

#define NALGOS 64
#define NTASKS 256
#define TSTEPS 4096
#define CHUNK  256                 // steps per expand block
#define NCHUNK (TSTEPS / CHUNK)    // 16
#define SUB    64                  // steps per expand LDS sub-tile
#define TP     257                 // expand tile pitch (t-major), odd -> conflict-free
#define LOG2E  1.44269504f

// ---------------- Phase 1: driver --------------------------------------------
// One wave per algorithm. Serial chain per step: rcp -> fma -> exp2 -> add.
// v2: row index for the tm prefetch is packed into ctab.w (arrives through the
// 4-deep ds_read_b128 pipeline -> no per-step immediate-use LDS read), tm
// pipeline deepened to 8, all stores hoisted to unconditional group boundaries,
// SALU-only addressing for the tm row load (readfirstlane + saddr form).
__global__ __launch_bounds__(64) void driver_kernel(
    const int* __restrict__ lx, const float* __restrict__ tmat,
    const float* __restrict__ diff, const float* __restrict__ eff_v,
    const float* __restrict__ mem_v, const float* __restrict__ boost_v,
    float* __restrict__ g_arr, float* __restrict__ ckpt) {
  __shared__ int    lx_s[TSTEPS + 16];
  __shared__ float  c_s[NTASKS];
  __shared__ float4 ctab[TSTEPS + 8];   // {c'_{t+1}, B_t, A0_t, lx[t+2] | lx[t+8]<<16}

  const int a = blockIdx.x;
  const int l = threadIdx.x;
  const float eff   = eff_v[a];
  const float mem   = mem_v[a];
  const float boost = boost_v[a];
  const float e0 = eff - boost;
  const float b2 = 2.0f * boost;

  // stage lx into LDS (coalesced)
#pragma unroll 8
  for (int k = 0; k < TSTEPS / 64; ++k) lx_s[k * 64 + l] = lx[k * 64 + l];
  if (l < 16) lx_s[TSTEPS + l] = 0;
  // c_s[n] = -log2e / diff[n]
#pragma unroll
  for (int k = 0; k < NTASKS / 64; ++k) {
    float dk = diff[k * 64 + l];
    c_s[k * 64 + l] = -LOG2E / dk;
  }
  __syncthreads();

  // build ctab
#pragma unroll 4
  for (int k = 0; k < TSTEPS / 64; ++k) {
    int i  = k * 64 + l;
    int t0 = lx_s[i];
    int t1 = lx_s[i + 1];
    float q  = tmat[t0 * NTASKS + t1];
    float cp = c_s[t1];
    float4 e;
    e.x = cp;
    e.y = b2 * cp * q;
    e.z = e0 * cp * q;
    e.w = __int_as_float(lx_s[i + 2] | (lx_s[i + 8] << 16));
    ctab[i] = e;
  }
  if (l < 8) ctab[TSTEPS + l] = make_float4(0.f, 0.f, 0.f, __int_as_float(0));
  __syncthreads();

  const float4* rows = (const float4*)tmat;  // row r: rows[r*64 + l] (4 cols/lane)
  float* gout = g_arr + (size_t)a * TSTEPS;
  float* ck   = ckpt  + (size_t)a * NCHUNK * NTASKS;

  float r0 = 0.f, r1 = 0.f, r2 = 0.f, r3 = 0.f;
  float u = 2.0f;                 // 1 + exp2(0): w_{-1} = 0.5 -> g_0 = eff
  float keep_g = 0.f;

  // pipelines: ctab 4-deep (slot = t&3), tm rows 8-deep (slot = t&7)
  float4 ctr[4];
  float4 tmr[8];
#pragma unroll
  for (int k = 0; k < 4; ++k) ctr[k] = ctab[k];
#pragma unroll
  for (int k = 0; k < 8; ++k) tmr[k] = rows[lx_s[k] * 64 + l];
  float A = ctr[0].z;             // A_0 (p_0 = 0)

  for (int grp = 0; grp < TSTEPS / 64; ++grp) {
    // 64-step group; inner 32 statically unrolled so every pipeline-register
    // index is compile-time (no scratch), back-edge wait drain amortized 1/32.
#pragma unroll 1
    for (int k32 = 0; k32 < 2; ++k32) {
      const float4* cb = ctab + grp * 64 + k32 * 32;
      const int kb = k32 * 32;
#pragma unroll
      for (int kk = 0; kk < 32; ++kk) {
        const int k = kb + kk;                 // step within group (kb SGPR, kk imm)
        const float4 ct  = ctr[k & 3];         // entry t     (loaded 4 steps ago)
        const float4 ctn = ctr[(k + 1) & 3];   // entry t+1   (loaded 3 steps ago)
        const float4 tm  = tmr[k & 7];         // row lx[t]   (loaded 8 steps ago)

        // ---- main serial chain ----
        float w   = __builtin_amdgcn_rcpf(u);      // w_{t-1}
        float gt  = fmaf(b2, w, e0);               // g_t
        float arg = fmaf(ct.y, w, A);              // c'_{t+1} * res_t[lx[t+1]]
        float ev  = __builtin_amdgcn_exp2f(arg);
        u = 1.0f + ev;

        // ---- off-chain ----
        keep_g = (k == l) ? gt : keep_g;

        r0 = fmaf(r0, mem, tm.x * gt);
        r1 = fmaf(r1, mem, tm.y * gt);
        r2 = fmaf(r2, mem, tm.z * gt);
        r3 = fmaf(r3, mem, tm.w * gt);

        // select res_t[lx[t+2]], broadcast from owner lane (SALU decode of ct.w)
        const int sw   = __builtin_amdgcn_readfirstlane(__float_as_int(ct.w));
        const int j2   = sw & 0xff;            // lx[t+2]
        const int lane = j2 >> 2;
        float h01  = (j2 & 1) ? r1 : r0;
        float h23  = (j2 & 1) ? r3 : r2;
        float hsel = (j2 & 2) ? h23 : h01;
        float bro = __uint_as_float(
            __builtin_amdgcn_readlane(__float_as_uint(hsel), lane));
        float p = mem * bro;                   // p_{t+1}
        A = fmaf(ctn.x, p, ctn.z);             // A_{t+1}

        // refill pipelines (consumed 4 / 8 steps from now)
        ctr[k & 3] = cb[kk + 4];
        const int nrow = (sw >> 16) & 0xff;    // lx[t+8], SALU -> saddr load
        tmr[k & 7] = rows[nrow * 64 + l];
      }
    }
    // unconditional group-boundary stores (keeps counted waitcnts clean)
    gout[grp * 64 + l] = keep_g;
    if ((grp & 3) == 3 && grp != 63) {
      float4 s; s.x = r0; s.y = r1; s.z = r2; s.w = r3;
      ((float4*)(ck + ((grp + 1) >> 2) * NTASKS))[l] = s;
    }
  }
}

// ---------------- Phase 2: expand --------------------------------------------
// v2: 1D grid with XCD-grouping swizzle — all 16 chunks of one algorithm land
// on the same XCD (blockIdx % 8 == a % 8), so the partial 128-B lines at the
// 256-B segment boundaries of one algorithm's output merge in a single L2.
__global__ __launch_bounds__(256) void expand_kernel(
    const int* __restrict__ lx, const float* __restrict__ tmat,
    const float* __restrict__ diff, const float* __restrict__ mem_v,
    const float* __restrict__ g_arr, const float* __restrict__ ckpt,
    float* __restrict__ out) {
  __shared__ float tile[SUB * TP];    // t-major: tile[ts*TP + n]
  __shared__ int   lx_c[CHUNK];
  __shared__ float g_c[CHUNK];

  const int id = blockIdx.x;          // 0..1023
  const int c  = (id >> 3) & 15;      // chunk 0..15
  const int a  = (id & 7) + 8 * (id >> 7);  // algorithm 0..63 (a%8 == id%8)
  const int n  = threadIdx.x;         // column 0..255

  const float mem = mem_v[a];
  const float cn  = -LOG2E / diff[n];
  float res = (c == 0) ? 0.f : ckpt[((size_t)a * NCHUNK + c) * NTASKS + n];

  const int t0 = c * CHUNK;
  lx_c[n] = lx[t0 + n];
  g_c[n]  = g_arr[(size_t)a * TSTEPS + t0 + n];
  __syncthreads();

  if (c == 0) out[((size_t)a * NTASKS + n) * (TSTEPS + 1)] = 0.f;

  const int tq   = threadIdx.x & 15;   // t-quad within run
  const int rloc = threadIdx.x >> 4;   // 0..15

  for (int tb = 0; tb < CHUNK; tb += SUB) {
    // compute 64 steps for own column
#pragma unroll 8
    for (int ts = 0; ts < SUB; ++ts) {
      int   task = lx_c[tb + ts];
      float g    = g_c[tb + ts];
      float tm   = tmat[task * NTASKS + n];
      res = fmaf(res, mem, tm * g);
      float w = __builtin_amdgcn_rcpf(
          1.0f + __builtin_amdgcn_exp2f(cn * res));
      tile[ts * TP + n] = fmaf(2.0f, w, -1.0f);   // sig
    }
    __syncthreads();
    // flush: 16 rows per iteration, float4 along t
    for (int rr = 0; rr < NTASKS; rr += 16) {
      const int row = rr + rloc;
      float v0 = tile[(4 * tq + 0) * TP + row];
      float v1 = tile[(4 * tq + 1) * TP + row];
      float v2 = tile[(4 * tq + 2) * TP + row];
      float v3 = tile[(4 * tq + 3) * TP + row];
      float4 v = make_float4(v0, v1, v2, v3);
      float* dst = &out[((size_t)a * NTASKS + row) * (TSTEPS + 1) +
                        t0 + tb + 4 * tq + 1];
      __builtin_memcpy(dst, &v, 16);   // dword-aligned wide store
    }
    __syncthreads();
  }
}

extern "C" void kernel_launch(void* const* d_in, const int* in_sizes, int n_in,
                              void* d_out, int out_size, void* d_ws, size_t ws_size,
                              hipStream_t stream) {
  const int*   lx    = (const int*)d_in[0];
  const float* tmat  = (const float*)d_in[1];
  const float* diff  = (const float*)d_in[2];
  const float* eff   = (const float*)d_in[3];
  const float* mem   = (const float*)d_in[4];
  const float* boost = (const float*)d_in[5];
  float* out = (float*)d_out;

  float* g_arr = (float*)d_ws;                      // 64*4096 f32 = 1 MB
  float* ckpt  = g_arr + (size_t)NALGOS * TSTEPS;   // 64*16*256 f32 = 1 MB

  driver_kernel<<<NALGOS, 64, 0, stream>>>(lx, tmat, diff, eff, mem, boost,
                                           g_arr, ckpt);
  expand_kernel<<<dim3(NCHUNK * NALGOS), 256, 0, stream>>>(
      lx, tmat, diff, mem, g_arr, ckpt, out);
}